// Round 1
// baseline (1232.144 us; speedup 1.0000x reference)
//
#include <hip/hip_runtime.h>

// Problem constants
constexpr int Bn   = 128;    // batch
constexpr int In   = 800;    // genes per case
constexpr int En   = 512;    // embed dim
constexpr int V1   = 19001;  // vocab + padding row
constexpr int NHn  = 8;      // heads
constexpr int NBn  = 4;      // attention blocks
constexpr int OUTn = 5000;   // output genes

// d_out layout (floats): preds [B,OUT] | attns [NB,B,I] | hiddens [NB,B,E]
constexpr int OFF_ATTN = Bn * OUTn;                 // 640000
constexpr int OFF_HID  = OFF_ATTN + NBn * Bn * In;  // 1049600

// ---------------------------------------------------------------------------
// K1: scoresv[nb][v][n] = tanh(T[nb][v] @ Wk[nb] + bk[nb]) @ Wq[nb] + bq[nb]
// Workgroup: 32 vocab rows x all 512 cols, 256 threads (4 waves).
// Each wave owns 8 rows; lane owns 8 consecutive cols. acc[8][8] per thread.
// ---------------------------------------------------------------------------
__global__ __launch_bounds__(256, 2)
void k_scores(const float* __restrict__ T, const float* __restrict__ Wk,
              const float* __restrict__ bk, const float* __restrict__ Wq,
              const float* __restrict__ bq, float* __restrict__ scoresv) {
    __shared__ float As[32 * En];  // 64 KB
    const int nb = blockIdx.y;
    const int v0 = blockIdx.x * 32;
    const float* Tb = T + (size_t)nb * V1 * En;
    const float* W  = Wk + (size_t)nb * En * En;

    // Stage 32 rows of T into LDS (zero-pad past V1)
    for (int idx = threadIdx.x; idx < 32 * 128; idx += 256) {
        const int row = idx >> 7;
        const int c4  = (idx & 127) << 2;
        const int vr  = v0 + row;
        float4 val = make_float4(0.f, 0.f, 0.f, 0.f);
        if (vr < V1) val = *(const float4*)(Tb + (size_t)vr * En + c4);
        *(float4*)(As + row * En + c4) = val;
    }
    __syncthreads();

    const int lane = threadIdx.x & 63;
    const int rgrp = threadIdx.x >> 6;  // wave id: rows rgrp*8 .. rgrp*8+7
    const int c0   = lane * 8;

    float acc[8][8];
#pragma unroll
    for (int r = 0; r < 8; ++r)
#pragma unroll
        for (int j = 0; j < 8; ++j) acc[r][j] = 0.f;

    for (int k = 0; k < En; k += 4) {
        float4 b0[4], b1[4];
#pragma unroll
        for (int kk = 0; kk < 4; ++kk) {
            b0[kk] = *(const float4*)(W + (size_t)(k + kk) * En + c0);
            b1[kk] = *(const float4*)(W + (size_t)(k + kk) * En + c0 + 4);
        }
#pragma unroll
        for (int r = 0; r < 8; ++r) {
            const float4 av = *(const float4*)(As + (rgrp * 8 + r) * En + k);
            const float a0 = av.x, a1 = av.y, a2 = av.z, a3 = av.w;
            acc[r][0] += a0 * b0[0].x + a1 * b0[1].x + a2 * b0[2].x + a3 * b0[3].x;
            acc[r][1] += a0 * b0[0].y + a1 * b0[1].y + a2 * b0[2].y + a3 * b0[3].y;
            acc[r][2] += a0 * b0[0].z + a1 * b0[1].z + a2 * b0[2].z + a3 * b0[3].z;
            acc[r][3] += a0 * b0[0].w + a1 * b0[1].w + a2 * b0[2].w + a3 * b0[3].w;
            acc[r][4] += a0 * b1[0].x + a1 * b1[1].x + a2 * b1[2].x + a3 * b1[3].x;
            acc[r][5] += a0 * b1[0].y + a1 * b1[1].y + a2 * b1[2].y + a3 * b1[3].y;
            acc[r][6] += a0 * b1[0].z + a1 * b1[1].z + a2 * b1[2].z + a3 * b1[3].z;
            acc[r][7] += a0 * b1[0].w + a1 * b1[1].w + a2 * b1[2].w + a3 * b1[3].w;
        }
    }

    // keys = tanh(acc + bk)   (in place)
    float bkv[8];
#pragma unroll
    for (int j = 0; j < 8; ++j) bkv[j] = bk[nb * En + c0 + j];
#pragma unroll
    for (int r = 0; r < 8; ++r)
#pragma unroll
        for (int j = 0; j < 8; ++j) acc[r][j] = tanhf(acc[r][j] + bkv[j]);

    // scores: per head, partial dot over this lane's 8 cols, butterfly over wave
    for (int n = 0; n < NHn; ++n) {
        float wq[8];
#pragma unroll
        for (int j = 0; j < 8; ++j)
            wq[j] = Wq[((size_t)nb * En + (c0 + j)) * NHn + n];
        float p[8];
#pragma unroll
        for (int r = 0; r < 8; ++r) {
            float s = 0.f;
#pragma unroll
            for (int j = 0; j < 8; ++j) s += acc[r][j] * wq[j];
            p[r] = s;
        }
#pragma unroll
        for (int m = 1; m < 64; m <<= 1) {
#pragma unroll
            for (int r = 0; r < 8; ++r) p[r] += __shfl_xor(p[r], m, 64);
        }
        if (lane == n) {
            const float bqn = bq[nb * NHn + n];
#pragma unroll
            for (int r = 0; r < 8; ++r) {
                const int vr = v0 + rgrp * 8 + r;
                if (vr < V1)
                    scoresv[((size_t)nb * V1 + vr) * NHn + n] = p[r] + bqn;
            }
        }
    }
}

// ---------------------------------------------------------------------------
// K2: masked softmax over genes, per (nb, b); writes attn weights (head-sum).
// ---------------------------------------------------------------------------
__global__ __launch_bounds__(256)
void k_softmax(const int* __restrict__ sga, const float* __restrict__ scoresv,
               float* __restrict__ attn_out) {
    const int b  = blockIdx.x;
    const int nb = blockIdx.y;
    const int tid = threadIdx.x;
    const int lane = tid & 63;
    const int wid  = tid >> 6;
    __shared__ float red[4 * NHn];

    float sc[4][NHn];
    int ivals[4];
#pragma unroll
    for (int s = 0; s < 4; ++s) {
        const int i = tid + s * 256;
        ivals[s] = i;
        if (i < In) {
            const int v = sga[b * In + i];
            const float4 s0 = *(const float4*)(scoresv + ((size_t)nb * V1 + v) * NHn);
            const float4 s1 = *(const float4*)(scoresv + ((size_t)nb * V1 + v) * NHn + 4);
            sc[s][0] = s0.x; sc[s][1] = s0.y; sc[s][2] = s0.z; sc[s][3] = s0.w;
            sc[s][4] = s1.x; sc[s][5] = s1.y; sc[s][6] = s1.z; sc[s][7] = s1.w;
            if (v == 0) {
#pragma unroll
                for (int n = 0; n < NHn; ++n) sc[s][n] = -1e9f;
            }
        } else {
#pragma unroll
            for (int n = 0; n < NHn; ++n) sc[s][n] = -3.0e38f;
        }
    }

    // --- max over genes per head ---
    float lm[NHn];
#pragma unroll
    for (int n = 0; n < NHn; ++n)
        lm[n] = fmaxf(fmaxf(sc[0][n], sc[1][n]), fmaxf(sc[2][n], sc[3][n]));
#pragma unroll
    for (int m = 1; m < 64; m <<= 1) {
#pragma unroll
        for (int n = 0; n < NHn; ++n) lm[n] = fmaxf(lm[n], __shfl_xor(lm[n], m, 64));
    }
    if (lane == 0) {
#pragma unroll
        for (int n = 0; n < NHn; ++n) red[wid * NHn + n] = lm[n];
    }
    __syncthreads();
    float M[NHn];
#pragma unroll
    for (int n = 0; n < NHn; ++n)
        M[n] = fmaxf(fmaxf(red[n], red[NHn + n]), fmaxf(red[2 * NHn + n], red[3 * NHn + n]));
    __syncthreads();

    // --- exp + sum ---
    float ls[NHn];
#pragma unroll
    for (int n = 0; n < NHn; ++n) ls[n] = 0.f;
#pragma unroll
    for (int s = 0; s < 4; ++s) {
#pragma unroll
        for (int n = 0; n < NHn; ++n) {
            sc[s][n] = expf(sc[s][n] - M[n]);  // invalid slots -> exp(-inf)=0
            ls[n] += sc[s][n];
        }
    }
#pragma unroll
    for (int m = 1; m < 64; m <<= 1) {
#pragma unroll
        for (int n = 0; n < NHn; ++n) ls[n] += __shfl_xor(ls[n], m, 64);
    }
    if (lane == 0) {
#pragma unroll
        for (int n = 0; n < NHn; ++n) red[wid * NHn + n] = ls[n];
    }
    __syncthreads();
    float inv[NHn];
#pragma unroll
    for (int n = 0; n < NHn; ++n) {
        const float S = red[n] + red[NHn + n] + red[2 * NHn + n] + red[3 * NHn + n];
        inv[n] = 1.0f / S;
    }

    // --- attn weight = sum over heads of A ---
#pragma unroll
    for (int s = 0; s < 4; ++s) {
        if (ivals[s] < In) {
            float w = 0.f;
#pragma unroll
            for (int n = 0; n < NHn; ++n) w += sc[s][n] * inv[n];
            attn_out[((size_t)nb * Bn + b) * In + ivals[s]] = w;
        }
    }
}

// ---------------------------------------------------------------------------
// K3: emb[nb][b][e] = sum_i w[nb,b,i] * T[nb][sga[b,i]][e]
// ---------------------------------------------------------------------------
__global__ __launch_bounds__(256)
void k_emb(const int* __restrict__ sga, const float* __restrict__ attn,
           const float* __restrict__ T, float* __restrict__ emb) {
    const int b  = blockIdx.x;
    const int nb = blockIdx.y;
    __shared__ int   sv[In];
    __shared__ float sw[In];
    for (int idx = threadIdx.x; idx < In; idx += 256) {
        sv[idx] = sga[b * In + idx];
        sw[idx] = attn[((size_t)nb * Bn + b) * In + idx];
    }
    __syncthreads();
    const float2* Tb = (const float2*)(T + (size_t)nb * V1 * En);
    float2 a = make_float2(0.f, 0.f);
#pragma unroll 4
    for (int i = 0; i < In; ++i) {
        const int v = sv[i];
        const float w = sw[i];
        const float2 t = Tb[(size_t)v * (En / 2) + threadIdx.x];
        a.x += w * t.x;
        a.y += w * t.y;
    }
    *(float2*)(emb + ((size_t)nb * Bn + b) * En + threadIdx.x * 2) = a;
}

// ---------------------------------------------------------------------------
// K4a: curr0 = relu(emb0 + can_emb[can]); hiddens[0] = curr0
// ---------------------------------------------------------------------------
__global__ __launch_bounds__(256)
void k_step0(const float* __restrict__ emb0, const int* __restrict__ can,
             const float* __restrict__ can_emb, float* __restrict__ cur,
             float* __restrict__ hid) {
    const int b = blockIdx.x;
    const int e0 = threadIdx.x * 2;
    const int c = can[b];
    float2 v = *(const float2*)(emb0 + (size_t)b * En + e0);
    const float2 ce = *(const float2*)(can_emb + (size_t)c * En + e0);
    v.x = fmaxf(v.x + ce.x, 0.f);
    v.y = fmaxf(v.y + ce.y, 0.f);
    *(float2*)(cur + (size_t)b * En + e0) = v;
    *(float2*)(hid + (size_t)b * En + e0) = v;
}

// ---------------------------------------------------------------------------
// K4b: curr = act(emb_i + prev @ Wh);  act: 0=relu, 1=sigmoid
// ---------------------------------------------------------------------------
__global__ __launch_bounds__(256)
void k_step(const float* __restrict__ embi, const float* __restrict__ prev,
            const float* __restrict__ Whi, float* __restrict__ cur,
            float* __restrict__ hid, const int sig) {
    const int b = blockIdx.x;
    __shared__ float cr[En];
    cr[threadIdx.x]       = prev[(size_t)b * En + threadIdx.x];
    cr[threadIdx.x + 256] = prev[(size_t)b * En + threadIdx.x + 256];
    __syncthreads();
    const int e0 = threadIdx.x * 2;
    float2 a = *(const float2*)(embi + (size_t)b * En + e0);
    const float2* Wp = (const float2*)Whi;
#pragma unroll 4
    for (int k = 0; k < En; ++k) {
        const float ck = cr[k];
        const float2 wv = Wp[(size_t)k * (En / 2) + threadIdx.x];
        a.x += ck * wv.x;
        a.y += ck * wv.y;
    }
    if (sig) {
        a.x = 1.0f / (1.0f + expf(-a.x));
        a.y = 1.0f / (1.0f + expf(-a.y));
    } else {
        a.x = fmaxf(a.x, 0.f);
        a.y = fmaxf(a.y, 0.f);
    }
    *(float2*)(cur + (size_t)b * En + e0) = a;
    *(float2*)(hid + (size_t)b * En + e0) = a;
}

// ---------------------------------------------------------------------------
// K5: preds = curr3 @ Wfinal   [128,512]@[512,5000]
// Tile: 32 rows x 64 cols per block; curr tile staged in LDS (64 KB).
// ---------------------------------------------------------------------------
__global__ __launch_bounds__(256, 2)
void k_preds(const float* __restrict__ cur, const float* __restrict__ Wf,
             float* __restrict__ preds) {
    __shared__ float cs[32 * En];  // 64 KB
    const int nt = blockIdx.x;  // col tile (64 cols)
    const int bt = blockIdx.y;  // row tile (32 rows)
    for (int idx = threadIdx.x; idx < 32 * 128; idx += 256) {
        const int row = idx >> 7;
        const int c4  = (idx & 127) << 2;
        *(float4*)(cs + row * En + c4) =
            *(const float4*)(cur + (size_t)(bt * 32 + row) * En + c4);
    }
    __syncthreads();
    const int lane = threadIdx.x & 63;
    const int rgrp = threadIdx.x >> 6;
    const int col = nt * 64 + lane;
    float acc[8];
#pragma unroll
    for (int j = 0; j < 8; ++j) acc[j] = 0.f;
    const bool ok = (col < OUTn);
    for (int k = 0; k < En; k += 4) {
        float w0 = 0.f, w1 = 0.f, w2 = 0.f, w3 = 0.f;
        if (ok) {
            w0 = Wf[(size_t)(k + 0) * OUTn + col];
            w1 = Wf[(size_t)(k + 1) * OUTn + col];
            w2 = Wf[(size_t)(k + 2) * OUTn + col];
            w3 = Wf[(size_t)(k + 3) * OUTn + col];
        }
#pragma unroll
        for (int j = 0; j < 8; ++j) {
            const float4 cv = *(const float4*)(cs + (rgrp * 8 + j) * En + k);
            acc[j] += cv.x * w0 + cv.y * w1 + cv.z * w2 + cv.w * w3;
        }
    }
    if (ok) {
#pragma unroll
        for (int j = 0; j < 8; ++j)
            preds[(size_t)(bt * 32 + rgrp * 8 + j) * OUTn + col] = acc[j];
    }
}

// ---------------------------------------------------------------------------
extern "C" void kernel_launch(void* const* d_in, const int* in_sizes, int n_in,
                              void* d_out, int out_size, void* d_ws, size_t ws_size,
                              hipStream_t stream) {
    const int*   sga     = (const int*)d_in[0];
    const int*   can     = (const int*)d_in[1];
    const float* T       = (const float*)d_in[2];
    const float* Wk      = (const float*)d_in[3];
    const float* bk      = (const float*)d_in[4];
    const float* Wq      = (const float*)d_in[5];
    const float* bq      = (const float*)d_in[6];
    const float* can_emb = (const float*)d_in[7];
    const float* Wh      = (const float*)d_in[8];
    const float* Wf      = (const float*)d_in[9];

    float* out = (float*)d_out;
    float* ws  = (float*)d_ws;

    // workspace layout (floats)
    float* scoresv = ws;                                // NB*V1*NH
    float* embw    = scoresv + (size_t)NBn * V1 * NHn;  // NB*B*E
    float* cur0    = embw + (size_t)NBn * Bn * En;      // B*E
    float* cur1    = cur0 + (size_t)Bn * En;            // B*E

    float* preds_out = out;
    float* attn_out  = out + OFF_ATTN;
    float* hid_out   = out + OFF_HID;

    // K1: vocab-space scores for all 4 blocks
    k_scores<<<dim3((V1 + 31) / 32, NBn), 256, 0, stream>>>(T, Wk, bk, Wq, bq, scoresv);
    // K2: softmax + head-sum -> attns (directly to d_out)
    k_softmax<<<dim3(Bn, NBn), 256, 0, stream>>>(sga, scoresv, attn_out);
    // K3: weighted embedding sums
    k_emb<<<dim3(Bn, NBn), 256, 0, stream>>>(sga, attn_out, T, embw);
    // K4: residual chain
    k_step0<<<Bn, 256, 0, stream>>>(embw, can, can_emb, cur0, hid_out);
    k_step<<<Bn, 256, 0, stream>>>(embw + 1 * Bn * En, cur0, Wh + 0 * En * En,
                                   cur1, hid_out + 1 * (size_t)Bn * En, 0);
    k_step<<<Bn, 256, 0, stream>>>(embw + 2 * Bn * En, cur1, Wh + 1 * En * En,
                                   cur0, hid_out + 2 * (size_t)Bn * En, 0);
    k_step<<<Bn, 256, 0, stream>>>(embw + 3 * Bn * En, cur0, Wh + 2 * En * En,
                                   cur1, hid_out + 3 * (size_t)Bn * En, 1);
    // K5: final projection
    k_preds<<<dim3((OUTn + 63) / 64, Bn / 32), 256, 0, stream>>>(cur1, Wf, preds_out);
}

// Round 2
// 762.184 us; speedup vs baseline: 1.6166x; 1.6166x over previous
//
#include <hip/hip_runtime.h>
#include <hip/hip_bf16.h>

// Problem constants
constexpr int Bn   = 128;    // batch
constexpr int In   = 800;    // genes per case
constexpr int En   = 512;    // embed dim
constexpr int V1   = 19001;  // vocab + padding row
constexpr int NHn  = 8;      // heads
constexpr int NBn  = 4;      // attention blocks
constexpr int OUTn = 5000;   // output genes

// d_out layout (floats): preds [B,OUT] | attns [NB,B,I] | hiddens [NB,B,E]
constexpr int OFF_ATTN = Bn * OUTn;                 // 640000
constexpr int OFF_HID  = OFF_ATTN + NBn * Bn * In;  // 1049600

typedef __attribute__((ext_vector_type(8))) short bf16x8;
typedef __attribute__((ext_vector_type(4))) float f32x4;

__device__ inline ushort f2bf(float x) {
    __hip_bfloat16 h = __float2bfloat16(x);
    return *reinterpret_cast<ushort*>(&h);
}

// ---------------------------------------------------------------------------
// K0: Wkt[nb][n][k] = bf16(Wk[nb][k][n])  (transpose + convert, 1M elements)
// ---------------------------------------------------------------------------
__global__ __launch_bounds__(256)
void k_prep(const float* __restrict__ Wk, ushort* __restrict__ Wkt) {
    const size_t idx = (size_t)blockIdx.x * 256 + threadIdx.x;  // 4*512*512
    const int nb = (int)(idx >> 18);
    const int k  = (int)(idx >> 9) & 511;
    const int n  = (int)idx & 511;
    // coalesced read over n, scattered write (L2 absorbs)
    const float v = Wk[(((size_t)nb * En) + k) * En + n];
    Wkt[(((size_t)nb * En) + n) * En + k] = f2bf(v);
}

// ---------------------------------------------------------------------------
// K1: scoresv[nb][v][h] = tanh(T[nb][v] @ Wk[nb] + bk[nb]) @ Wq[nb] + bq[nb]
// MFMA bf16 16x16x32. Block tile M=64 x N=512, BK=32. 4 waves; each wave
// owns all 64 rows x 128 cols (4 m-tiles x 8 n-tiles, 128 acc VGPRs).
// LDS frag layout [kchunk][row][8] -> b128 reads 2-way bank aliasing (free).
// Stage 2 (scores @ Wq, 1/64 the FLOPs) in-register + butterfly + LDS reduce.
// ---------------------------------------------------------------------------
__global__ __launch_bounds__(256, 2)
void k_scores(const float* __restrict__ T, const ushort* __restrict__ Wkt,
              const float* __restrict__ bk, const float* __restrict__ Wq,
              const float* __restrict__ bq, float* __restrict__ scoresv) {
    __shared__ ushort A_s[4][64][8];    // 4 KB   A[m][k]: chunk q holds k=q*8..+7
    __shared__ ushort B_s[4][512][8];   // 32 KB  B[k][n] stored n-major per chunk
    __shared__ float  red[4][64][NHn];  // 8 KB   per-wave score partials

    const int nb  = blockIdx.y;
    const int v0  = blockIdx.x * 64;
    const int tid = threadIdx.x;
    const int lane = tid & 63;
    const int wid  = tid >> 6;   // wave id = n-quarter (cols wid*128..+128)
    const int q    = lane >> 4;  // k-chunk for frags
    const int c    = lane & 15;

    const float*  Tb = T   + (size_t)nb * V1 * En;
    const ushort* Wn = Wkt + (size_t)nb * En * En;

    f32x4 acc[4][8];
#pragma unroll
    for (int mt = 0; mt < 4; ++mt)
#pragma unroll
        for (int nt = 0; nt < 8; ++nt) acc[mt][nt] = (f32x4)0.0f;

    for (int k0 = 0; k0 < En; k0 += 32) {
        // --- stage A: 64 rows x 32 k, fp32 -> bf16 (coalesced: 4 thr/row) ---
        {
            const int r  = tid >> 2;   // 0..63
            const int kq = tid & 3;    // 8-float chunk
            const int vr = v0 + r;
            float4 f0 = make_float4(0.f, 0.f, 0.f, 0.f), f1 = f0;
            if (vr < V1) {
                const float* p = Tb + (size_t)vr * En + k0 + kq * 8;
                f0 = *(const float4*)p;
                f1 = *(const float4*)(p + 4);
            }
            ushort4 u0, u1;
            u0.x = f2bf(f0.x); u0.y = f2bf(f0.y); u0.z = f2bf(f0.z); u0.w = f2bf(f0.w);
            u1.x = f2bf(f1.x); u1.y = f2bf(f1.y); u1.z = f2bf(f1.z); u1.w = f2bf(f1.w);
            *(ushort4*)&A_s[kq][r][0] = u0;
            *(ushort4*)&A_s[kq][r][4] = u1;
        }
        // --- stage B: 32 k x 512 n from pre-transposed bf16 Wkt[n][k] ---
        {
            const int w = wid, l = lane;   // wave w stages k-chunk w
#pragma unroll
            for (int i = 0; i < 8; ++i) {
                const int n = l + i * 64;
                *(uint4*)&B_s[w][n][0] =
                    *(const uint4*)(Wn + (size_t)n * En + k0 + w * 8);
            }
        }
        __syncthreads();

        bf16x8 aF[4];
#pragma unroll
        for (int mt = 0; mt < 4; ++mt)
            aF[mt] = *(bf16x8*)&A_s[q][mt * 16 + c][0];
#pragma unroll
        for (int nt = 0; nt < 8; ++nt) {
            const bf16x8 bF = *(bf16x8*)&B_s[q][wid * 128 + nt * 16 + c][0];
#pragma unroll
            for (int mt = 0; mt < 4; ++mt)
                acc[mt][nt] = __builtin_amdgcn_mfma_f32_16x16x32_bf16(
                    aF[mt], bF, acc[mt][nt], 0, 0, 0);
        }
        __syncthreads();
    }

    // --- keys = tanh(acc + bk[col]) in-register ---
#pragma unroll
    for (int nt = 0; nt < 8; ++nt) {
        const int col = wid * 128 + nt * 16 + c;
        const float bkv = bk[nb * En + col];
#pragma unroll
        for (int mt = 0; mt < 4; ++mt)
#pragma unroll
            for (int r = 0; r < 4; ++r)
                acc[mt][nt][r] = tanhf(acc[mt][nt][r] + bkv);
    }

    // --- stage 2: scores[row][h] = sum_col keys[row][col]*Wq[col][h] ---
    // C layout: row = mt*16 + q*4 + r, col = wid*128 + nt*16 + c
    for (int h = 0; h < NHn; ++h) {
        float wqh[8];
#pragma unroll
        for (int nt = 0; nt < 8; ++nt) {
            const int col = wid * 128 + nt * 16 + c;
            wqh[nt] = Wq[((size_t)nb * En + col) * NHn + h];
        }
        float p[4][4];
#pragma unroll
        for (int mt = 0; mt < 4; ++mt)
#pragma unroll
            for (int r = 0; r < 4; ++r) {
                float s = 0.f;
#pragma unroll
                for (int nt = 0; nt < 8; ++nt) s += acc[mt][nt][r] * wqh[nt];
                p[mt][r] = s;
            }
        // butterfly over the 16 lanes sharing this quad (masks 1,2,4,8)
#pragma unroll
        for (int m = 1; m < 16; m <<= 1) {
#pragma unroll
            for (int mt = 0; mt < 4; ++mt)
#pragma unroll
                for (int r = 0; r < 4; ++r)
                    p[mt][r] += __shfl_xor(p[mt][r], m, 64);
        }
        if (c == h) {
#pragma unroll
            for (int mt = 0; mt < 4; ++mt)
#pragma unroll
                for (int r = 0; r < 4; ++r)
                    red[wid][mt * 16 + q * 4 + r][h] = p[mt][r];
        }
    }
    __syncthreads();

    // --- cross-wave reduce + bq, write scores ---
    for (int idx = tid; idx < 64 * NHn; idx += 256) {
        const int row = idx >> 3;
        const int h   = idx & 7;
        const int vr  = v0 + row;
        if (vr < V1) {
            const float s = red[0][row][h] + red[1][row][h] +
                            red[2][row][h] + red[3][row][h] + bq[nb * NHn + h];
            scoresv[((size_t)nb * V1 + vr) * NHn + h] = s;
        }
    }
}

// ---------------------------------------------------------------------------
// K2: masked softmax over genes, per (nb, b); writes attn weights (head-sum).
// ---------------------------------------------------------------------------
__global__ __launch_bounds__(256)
void k_softmax(const int* __restrict__ sga, const float* __restrict__ scoresv,
               float* __restrict__ attn_out) {
    const int b  = blockIdx.x;
    const int nb = blockIdx.y;
    const int tid = threadIdx.x;
    const int lane = tid & 63;
    const int wid  = tid >> 6;
    __shared__ float red[4 * NHn];

    float sc[4][NHn];
    int ivals[4];
#pragma unroll
    for (int s = 0; s < 4; ++s) {
        const int i = tid + s * 256;
        ivals[s] = i;
        if (i < In) {
            const int v = sga[b * In + i];
            const float4 s0 = *(const float4*)(scoresv + ((size_t)nb * V1 + v) * NHn);
            const float4 s1 = *(const float4*)(scoresv + ((size_t)nb * V1 + v) * NHn + 4);
            sc[s][0] = s0.x; sc[s][1] = s0.y; sc[s][2] = s0.z; sc[s][3] = s0.w;
            sc[s][4] = s1.x; sc[s][5] = s1.y; sc[s][6] = s1.z; sc[s][7] = s1.w;
            if (v == 0) {
#pragma unroll
                for (int n = 0; n < NHn; ++n) sc[s][n] = -1e9f;
            }
        } else {
#pragma unroll
            for (int n = 0; n < NHn; ++n) sc[s][n] = -3.0e38f;
        }
    }

    float lm[NHn];
#pragma unroll
    for (int n = 0; n < NHn; ++n)
        lm[n] = fmaxf(fmaxf(sc[0][n], sc[1][n]), fmaxf(sc[2][n], sc[3][n]));
#pragma unroll
    for (int m = 1; m < 64; m <<= 1) {
#pragma unroll
        for (int n = 0; n < NHn; ++n) lm[n] = fmaxf(lm[n], __shfl_xor(lm[n], m, 64));
    }
    if (lane == 0) {
#pragma unroll
        for (int n = 0; n < NHn; ++n) red[wid * NHn + n] = lm[n];
    }
    __syncthreads();
    float M[NHn];
#pragma unroll
    for (int n = 0; n < NHn; ++n)
        M[n] = fmaxf(fmaxf(red[n], red[NHn + n]), fmaxf(red[2 * NHn + n], red[3 * NHn + n]));
    __syncthreads();

    float ls[NHn];
#pragma unroll
    for (int n = 0; n < NHn; ++n) ls[n] = 0.f;
#pragma unroll
    for (int s = 0; s < 4; ++s) {
#pragma unroll
        for (int n = 0; n < NHn; ++n) {
            sc[s][n] = expf(sc[s][n] - M[n]);
            ls[n] += sc[s][n];
        }
    }
#pragma unroll
    for (int m = 1; m < 64; m <<= 1) {
#pragma unroll
        for (int n = 0; n < NHn; ++n) ls[n] += __shfl_xor(ls[n], m, 64);
    }
    if (lane == 0) {
#pragma unroll
        for (int n = 0; n < NHn; ++n) red[wid * NHn + n] = ls[n];
    }
    __syncthreads();
    float inv[NHn];
#pragma unroll
    for (int n = 0; n < NHn; ++n) {
        const float S = red[n] + red[NHn + n] + red[2 * NHn + n] + red[3 * NHn + n];
        inv[n] = 1.0f / S;
    }

#pragma unroll
    for (int s = 0; s < 4; ++s) {
        if (ivals[s] < In) {
            float w = 0.f;
#pragma unroll
            for (int n = 0; n < NHn; ++n) w += sc[s][n] * inv[n];
            attn_out[((size_t)nb * Bn + b) * In + ivals[s]] = w;
        }
    }
}

// ---------------------------------------------------------------------------
// K3: emb[nb][b][e] = sum_i w[nb,b,i] * T[nb][sga[b,i]][e]
// ---------------------------------------------------------------------------
__global__ __launch_bounds__(256)
void k_emb(const int* __restrict__ sga, const float* __restrict__ attn,
           const float* __restrict__ T, float* __restrict__ emb) {
    const int b  = blockIdx.x;
    const int nb = blockIdx.y;
    __shared__ int   sv[In];
    __shared__ float sw[In];
    for (int idx = threadIdx.x; idx < In; idx += 256) {
        sv[idx] = sga[b * In + idx];
        sw[idx] = attn[((size_t)nb * Bn + b) * In + idx];
    }
    __syncthreads();
    const float2* Tb = (const float2*)(T + (size_t)nb * V1 * En);
    float2 a = make_float2(0.f, 0.f);
#pragma unroll 4
    for (int i = 0; i < In; ++i) {
        const int v = sv[i];
        const float w = sw[i];
        const float2 t = Tb[(size_t)v * (En / 2) + threadIdx.x];
        a.x += w * t.x;
        a.y += w * t.y;
    }
    *(float2*)(emb + ((size_t)nb * Bn + b) * En + threadIdx.x * 2) = a;
}

// ---------------------------------------------------------------------------
// K4a: curr0 = relu(emb0 + can_emb[can]); hiddens[0] = curr0
// ---------------------------------------------------------------------------
__global__ __launch_bounds__(256)
void k_step0(const float* __restrict__ emb0, const int* __restrict__ can,
             const float* __restrict__ can_emb, float* __restrict__ cur,
             float* __restrict__ hid) {
    const int b = blockIdx.x;
    const int e0 = threadIdx.x * 2;
    const int c = can[b];
    float2 v = *(const float2*)(emb0 + (size_t)b * En + e0);
    const float2 ce = *(const float2*)(can_emb + (size_t)c * En + e0);
    v.x = fmaxf(v.x + ce.x, 0.f);
    v.y = fmaxf(v.y + ce.y, 0.f);
    *(float2*)(cur + (size_t)b * En + e0) = v;
    *(float2*)(hid + (size_t)b * En + e0) = v;
}

// ---------------------------------------------------------------------------
// K4b: curr = act(emb_i + prev @ Wh);  act: 0=relu, 1=sigmoid
// ---------------------------------------------------------------------------
__global__ __launch_bounds__(256)
void k_step(const float* __restrict__ embi, const float* __restrict__ prev,
            const float* __restrict__ Whi, float* __restrict__ cur,
            float* __restrict__ hid, const int sig) {
    const int b = blockIdx.x;
    __shared__ float cr[En];
    cr[threadIdx.x]       = prev[(size_t)b * En + threadIdx.x];
    cr[threadIdx.x + 256] = prev[(size_t)b * En + threadIdx.x + 256];
    __syncthreads();
    const int e0 = threadIdx.x * 2;
    float2 a = *(const float2*)(embi + (size_t)b * En + e0);
    const float2* Wp = (const float2*)Whi;
#pragma unroll 4
    for (int k = 0; k < En; ++k) {
        const float ck = cr[k];
        const float2 wv = Wp[(size_t)k * (En / 2) + threadIdx.x];
        a.x += ck * wv.x;
        a.y += ck * wv.y;
    }
    if (sig) {
        a.x = 1.0f / (1.0f + expf(-a.x));
        a.y = 1.0f / (1.0f + expf(-a.y));
    } else {
        a.x = fmaxf(a.x, 0.f);
        a.y = fmaxf(a.y, 0.f);
    }
    *(float2*)(cur + (size_t)b * En + e0) = a;
    *(float2*)(hid + (size_t)b * En + e0) = a;
}

// ---------------------------------------------------------------------------
// K5: preds = curr3 @ Wfinal   [128,512]@[512,5000]
// ---------------------------------------------------------------------------
__global__ __launch_bounds__(256, 2)
void k_preds(const float* __restrict__ cur, const float* __restrict__ Wf,
             float* __restrict__ preds) {
    __shared__ float cs[32 * En];  // 64 KB
    const int nt = blockIdx.x;  // col tile (64 cols)
    const int bt = blockIdx.y;  // row tile (32 rows)
    for (int idx = threadIdx.x; idx < 32 * 128; idx += 256) {
        const int row = idx >> 7;
        const int c4  = (idx & 127) << 2;
        *(float4*)(cs + row * En + c4) =
            *(const float4*)(cur + (size_t)(bt * 32 + row) * En + c4);
    }
    __syncthreads();
    const int lane = threadIdx.x & 63;
    const int rgrp = threadIdx.x >> 6;
    const int col = nt * 64 + lane;
    float acc[8];
#pragma unroll
    for (int j = 0; j < 8; ++j) acc[j] = 0.f;
    const bool ok = (col < OUTn);
    for (int k = 0; k < En; k += 4) {
        float w0 = 0.f, w1 = 0.f, w2 = 0.f, w3 = 0.f;
        if (ok) {
            w0 = Wf[(size_t)(k + 0) * OUTn + col];
            w1 = Wf[(size_t)(k + 1) * OUTn + col];
            w2 = Wf[(size_t)(k + 2) * OUTn + col];
            w3 = Wf[(size_t)(k + 3) * OUTn + col];
        }
#pragma unroll
        for (int j = 0; j < 8; ++j) {
            const float4 cv = *(const float4*)(cs + (rgrp * 8 + j) * En + k);
            acc[j] += cv.x * w0 + cv.y * w1 + cv.z * w2 + cv.w * w3;
        }
    }
    if (ok) {
#pragma unroll
        for (int j = 0; j < 8; ++j)
            preds[(size_t)(bt * 32 + rgrp * 8 + j) * OUTn + col] = acc[j];
    }
}

// ---------------------------------------------------------------------------
extern "C" void kernel_launch(void* const* d_in, const int* in_sizes, int n_in,
                              void* d_out, int out_size, void* d_ws, size_t ws_size,
                              hipStream_t stream) {
    const int*   sga     = (const int*)d_in[0];
    const int*   can     = (const int*)d_in[1];
    const float* T       = (const float*)d_in[2];
    const float* Wk      = (const float*)d_in[3];
    const float* bk      = (const float*)d_in[4];
    const float* Wq      = (const float*)d_in[5];
    const float* bq      = (const float*)d_in[6];
    const float* can_emb = (const float*)d_in[7];
    const float* Wh      = (const float*)d_in[8];
    const float* Wf      = (const float*)d_in[9];

    float* out = (float*)d_out;
    float* ws  = (float*)d_ws;

    // workspace layout (floats; all offsets 16B-aligned)
    float* scoresv = ws;                                // NB*V1*NH   = 608032
    float* embw    = scoresv + (size_t)NBn * V1 * NHn;  // NB*B*E     = 262144
    float* cur0    = embw + (size_t)NBn * Bn * En;      // B*E
    float* cur1    = cur0 + (size_t)Bn * En;            // B*E
    ushort* Wkt    = (ushort*)(cur1 + (size_t)Bn * En); // NB*E*E bf16 = 2 MB

    float* preds_out = out;
    float* attn_out  = out + OFF_ATTN;
    float* hid_out   = out + OFF_HID;

    // K0: Wk -> bf16 transposed [nb][n][k]
    k_prep<<<(NBn * En * En) / 256, 256, 0, stream>>>(Wk, Wkt);
    // K1: vocab-space scores via MFMA
    k_scores<<<dim3((V1 + 63) / 64, NBn), 256, 0, stream>>>(T, Wkt, bk, Wq, bq, scoresv);
    // K2: softmax + head-sum -> attns (directly to d_out)
    k_softmax<<<dim3(Bn, NBn), 256, 0, stream>>>(sga, scoresv, attn_out);
    // K3: weighted embedding sums
    k_emb<<<dim3(Bn, NBn), 256, 0, stream>>>(sga, attn_out, T, embw);
    // K4: residual chain
    k_step0<<<Bn, 256, 0, stream>>>(embw, can, can_emb, cur0, hid_out);
    k_step<<<Bn, 256, 0, stream>>>(embw + 1 * Bn * En, cur0, Wh + 0 * En * En,
                                   cur1, hid_out + 1 * (size_t)Bn * En, 0);
    k_step<<<Bn, 256, 0, stream>>>(embw + 2 * Bn * En, cur1, Wh + 1 * En * En,
                                   cur0, hid_out + 2 * (size_t)Bn * En, 0);
    k_step<<<Bn, 256, 0, stream>>>(embw + 3 * Bn * En, cur0, Wh + 2 * En * En,
                                   cur1, hid_out + 3 * (size_t)Bn * En, 1);
    // K5: final projection
    k_preds<<<dim3((OUTn + 63) / 64, Bn / 32), 256, 0, stream>>>(cur1, Wf, preds_out);
}

// Round 3
// 747.675 us; speedup vs baseline: 1.6480x; 1.0194x over previous
//
#include <hip/hip_runtime.h>
#include <hip/hip_bf16.h>

// Problem constants
constexpr int Bn   = 128;    // batch
constexpr int In   = 800;    // genes per case
constexpr int En   = 512;    // embed dim
constexpr int V1   = 19001;  // vocab + padding row
constexpr int NHn  = 8;      // heads
constexpr int NBn  = 4;      // attention blocks
constexpr int OUTn = 5000;   // output genes

// d_out layout (floats): preds [B,OUT] | attns [NB,B,I] | hiddens [NB,B,E]
constexpr int OFF_ATTN = Bn * OUTn;                 // 640000
constexpr int OFF_HID  = OFF_ATTN + NBn * Bn * In;  // 1049600

typedef __attribute__((ext_vector_type(8))) short bf16x8;
typedef __attribute__((ext_vector_type(8))) unsigned short u16x8;
typedef __attribute__((ext_vector_type(4))) float f32x4;

__device__ inline ushort f2bf(float x) {
    __hip_bfloat16 h = __float2bfloat16(x);
    return *reinterpret_cast<ushort*>(&h);
}

__device__ inline void gl_lds16(const ushort* g, ushort* l) {
    __builtin_amdgcn_global_load_lds(
        (const __attribute__((address_space(1))) void*)g,
        (__attribute__((address_space(3))) void*)l, 16, 0, 0);
}

// ---------------------------------------------------------------------------
// K0: Wkt[nb][n][k] = bf16(Wk[nb][k][n]) via LDS tile transpose (coalesced IO)
// grid (8 n-tiles, 8 k-tiles, 4 nb), 256 threads, 64x64 tile
// ---------------------------------------------------------------------------
__global__ __launch_bounds__(256)
void k_prep(const float* __restrict__ Wk, ushort* __restrict__ Wkt) {
    __shared__ float ts[64][65];
    const int n0 = blockIdx.x * 64, k0 = blockIdx.y * 64, nb = blockIdx.z;
    const int t = threadIdx.x;
    {
        const int kr = t >> 2, nc = (t & 3) * 16;
        const float* p = Wk + (((size_t)nb * En) + (k0 + kr)) * En + n0 + nc;
#pragma unroll
        for (int j = 0; j < 4; ++j) {
            const float4 v = *(const float4*)(p + j * 4);
            ts[kr][nc + j * 4 + 0] = v.x; ts[kr][nc + j * 4 + 1] = v.y;
            ts[kr][nc + j * 4 + 2] = v.z; ts[kr][nc + j * 4 + 3] = v.w;
        }
    }
    __syncthreads();
    {
        const int nr = t >> 2, kc = (t & 3) * 16;
        ushort* d = Wkt + (((size_t)nb * En) + (n0 + nr)) * En + k0 + kc;
        ushort4 o;
#pragma unroll
        for (int j = 0; j < 4; ++j) {
            o.x = f2bf(ts[kc + j * 4 + 0][nr]); o.y = f2bf(ts[kc + j * 4 + 1][nr]);
            o.z = f2bf(ts[kc + j * 4 + 2][nr]); o.w = f2bf(ts[kc + j * 4 + 3][nr]);
            *(ushort4*)(d + j * 4) = o;
        }
    }
}

// ---------------------------------------------------------------------------
// k_zero: zero scoresv (atomics accumulate into it)
// ---------------------------------------------------------------------------
__global__ __launch_bounds__(256)
void k_zero(float* __restrict__ p, int n) {
    const int i = blockIdx.x * 256 + threadIdx.x;
    if (i < n) p[i] = 0.f;
}

// ---------------------------------------------------------------------------
// K1: m97-style GEMM: keys = tanh(T@Wk + bk); partial scores = keys@Wq
//     atomically accumulated into scoresv (bq dropped: cancels in softmax).
// Block = 128 rows x 128 cols, BK=32, 4 waves 2x2, wave tile 64x64.
// B staged via global_load_lds (bf16 Wkt); A staged manually fp32->bf16.
// Epilogue: tanh keys -> LDS (B-operand layout) -> MFMA vs WqT -> atomics.
// ---------------------------------------------------------------------------
__global__ __launch_bounds__(256, 3)
void k_scores(const float* __restrict__ T, const ushort* __restrict__ Wkt,
              const float* __restrict__ bk, const float* __restrict__ Wq,
              float* __restrict__ scoresv) {
    __shared__ union {
        struct { ushort A[128 * 40]; ushort B[128 * 32]; } s1;  // 18432 B
        ushort Ks[4][64 * 72];                                  // 36864 B
    } u;
    __shared__ ushort WqT[2][16 * 72];  // 4608 B

    const int mblk = blockIdx.x, nblk = blockIdx.y, nb = blockIdx.z;
    const int v0 = mblk * 128;
    const int tid = threadIdx.x, lane = tid & 63, wid = tid >> 6;
    const int wm = wid & 1, wn = wid >> 1;
    const int q = lane >> 4, c = lane & 15;

    const float*  Tb = T + (size_t)nb * V1 * En;
    const ushort* Wn = Wkt + (size_t)nb * En * En;

    // --- stage WqT: block's 128 cols x 16 heads (8 real + 8 zero), bf16 ---
    {
        const int cl = tid >> 1, hh = (tid & 1) * 4;
        const float4 wv =
            *(const float4*)(Wq + ((size_t)nb * En + nblk * 128 + cl) * NHn + hh);
        WqT[cl >> 6][(hh + 0) * 72 + (cl & 63)] = f2bf(wv.x);
        WqT[cl >> 6][(hh + 1) * 72 + (cl & 63)] = f2bf(wv.y);
        WqT[cl >> 6][(hh + 2) * 72 + (cl & 63)] = f2bf(wv.z);
        WqT[cl >> 6][(hh + 3) * 72 + (cl & 63)] = f2bf(wv.w);
        if (tid < 128) {
            const int half = tid >> 6, kl = tid & 63;
#pragma unroll
            for (int h2 = 8; h2 < 16; ++h2) WqT[half][h2 * 72 + kl] = 0;
        }
    }

    f32x4 acc[4][4];
#pragma unroll
    for (int mt = 0; mt < 4; ++mt)
#pragma unroll
        for (int nt = 0; nt < 4; ++nt) acc[mt][nt] = (f32x4)0.0f;

    const int arow = tid >> 1, akh = tid & 1;  // A-staging map
    const int vra = v0 + arow;

    for (int k0 = 0; k0 < En; k0 += 32) {
        __syncthreads();
        // --- A stage: 128 rows x 32 k fp32 -> bf16, LDS stride 40 ---
        {
            float4 f0 = make_float4(0, 0, 0, 0), f1 = f0, f2 = f0, f3 = f0;
            if (vra < V1) {
                const float* p = Tb + (size_t)vra * En + k0 + akh * 16;
                f0 = *(const float4*)p;       f1 = *(const float4*)(p + 4);
                f2 = *(const float4*)(p + 8); f3 = *(const float4*)(p + 12);
            }
            u16x8 o0, o1;
            o0[0] = f2bf(f0.x); o0[1] = f2bf(f0.y); o0[2] = f2bf(f0.z); o0[3] = f2bf(f0.w);
            o0[4] = f2bf(f1.x); o0[5] = f2bf(f1.y); o0[6] = f2bf(f1.z); o0[7] = f2bf(f1.w);
            o1[0] = f2bf(f2.x); o1[1] = f2bf(f2.y); o1[2] = f2bf(f2.z); o1[3] = f2bf(f2.w);
            o1[4] = f2bf(f3.x); o1[5] = f2bf(f3.y); o1[6] = f2bf(f3.z); o1[7] = f2bf(f3.w);
            ushort* d = u.s1.A + arow * 40 + akh * 16;
            *(u16x8*)d = o0;
            *(u16x8*)(d + 8) = o1;
        }
        // --- B stage: 32 k x 128 n via global_load_lds (2 insts/wave) ---
#pragma unroll
        for (int j = 0; j < 2; ++j) {
            const int bn = (wid * 2 + j) * 16;
            const ushort* gp = Wn + (size_t)(nblk * 128 + bn + (lane >> 2)) * En +
                               k0 + (lane & 3) * 8;
            gl_lds16(gp, u.s1.B + bn * 32);
        }
        __syncthreads();

        bf16x8 aF[4], bF[4];
#pragma unroll
        for (int mt = 0; mt < 4; ++mt)
            aF[mt] = *(bf16x8*)&u.s1.A[(wm * 64 + mt * 16 + c) * 40 + q * 8];
#pragma unroll
        for (int nt = 0; nt < 4; ++nt)
            bF[nt] = *(bf16x8*)&u.s1.B[(wn * 64 + nt * 16 + c) * 32 + q * 8];
#pragma unroll
        for (int nt = 0; nt < 4; ++nt)
#pragma unroll
            for (int mt = 0; mt < 4; ++mt)
                acc[mt][nt] = __builtin_amdgcn_mfma_f32_16x16x32_bf16(
                    aF[mt], bF[nt], acc[mt][nt], 0, 0, 0);
    }

    __syncthreads();  // all frag reads done before Ks overlays A/B region

    // --- tanh + write keys to LDS (row-major [64][72] bf16, wave-private) ---
#pragma unroll
    for (int nt = 0; nt < 4; ++nt) {
        const int col = nblk * 128 + wn * 64 + nt * 16 + c;
        const float bkv = bk[nb * En + col];
#pragma unroll
        for (int mt = 0; mt < 4; ++mt)
#pragma unroll
            for (int r = 0; r < 4; ++r) {
                const float kv = tanhf(acc[mt][nt][r] + bkv);
                u.Ks[wid][(mt * 16 + q * 4 + r) * 72 + nt * 16 + c] = f2bf(kv);
            }
    }

    // --- stage 2: D[h][row] = sum_colchunk WqT[h][k] * keys[row][k] ---
    f32x4 c2[4];
#pragma unroll
    for (int nt2 = 0; nt2 < 4; ++nt2) c2[nt2] = (f32x4)0.0f;
#pragma unroll
    for (int kk = 0; kk < 2; ++kk) {
        const bf16x8 aW = *(bf16x8*)&WqT[wn][c * 72 + kk * 32 + q * 8];
#pragma unroll
        for (int nt2 = 0; nt2 < 4; ++nt2) {
            const bf16x8 bK =
                *(bf16x8*)&u.Ks[wid][(nt2 * 16 + c) * 72 + kk * 32 + q * 8];
            c2[nt2] = __builtin_amdgcn_mfma_f32_16x16x32_bf16(aW, bK, c2[nt2], 0, 0, 0);
        }
    }
    // D layout: head = q*4+r (valid q<2), gene-row = nt2*16 + c
    if (q < 2) {
#pragma unroll
        for (int nt2 = 0; nt2 < 4; ++nt2) {
            const int vr = v0 + wm * 64 + nt2 * 16 + c;
            if (vr < V1) {
                float* dst = scoresv + ((size_t)nb * V1 + vr) * NHn + q * 4;
#pragma unroll
                for (int r = 0; r < 4; ++r) atomicAdd(dst + r, c2[nt2][r]);
            }
        }
    }
}

// ---------------------------------------------------------------------------
// K2: masked softmax over genes, per (nb, b); writes attn weights (head-sum).
// ---------------------------------------------------------------------------
__global__ __launch_bounds__(256)
void k_softmax(const int* __restrict__ sga, const float* __restrict__ scoresv,
               float* __restrict__ attn_out) {
    const int b  = blockIdx.x;
    const int nb = blockIdx.y;
    const int tid = threadIdx.x;
    const int lane = tid & 63;
    const int wid  = tid >> 6;
    __shared__ float red[4 * NHn];

    float sc[4][NHn];
    int ivals[4];
#pragma unroll
    for (int s = 0; s < 4; ++s) {
        const int i = tid + s * 256;
        ivals[s] = i;
        if (i < In) {
            const int v = sga[b * In + i];
            const float4 s0 = *(const float4*)(scoresv + ((size_t)nb * V1 + v) * NHn);
            const float4 s1 = *(const float4*)(scoresv + ((size_t)nb * V1 + v) * NHn + 4);
            sc[s][0] = s0.x; sc[s][1] = s0.y; sc[s][2] = s0.z; sc[s][3] = s0.w;
            sc[s][4] = s1.x; sc[s][5] = s1.y; sc[s][6] = s1.z; sc[s][7] = s1.w;
            if (v == 0) {
#pragma unroll
                for (int n = 0; n < NHn; ++n) sc[s][n] = -1e9f;
            }
        } else {
#pragma unroll
            for (int n = 0; n < NHn; ++n) sc[s][n] = -3.0e38f;
        }
    }

    float lm[NHn];
#pragma unroll
    for (int n = 0; n < NHn; ++n)
        lm[n] = fmaxf(fmaxf(sc[0][n], sc[1][n]), fmaxf(sc[2][n], sc[3][n]));
#pragma unroll
    for (int m = 1; m < 64; m <<= 1) {
#pragma unroll
        for (int n = 0; n < NHn; ++n) lm[n] = fmaxf(lm[n], __shfl_xor(lm[n], m, 64));
    }
    if (lane == 0) {
#pragma unroll
        for (int n = 0; n < NHn; ++n) red[wid * NHn + n] = lm[n];
    }
    __syncthreads();
    float M[NHn];
#pragma unroll
    for (int n = 0; n < NHn; ++n)
        M[n] = fmaxf(fmaxf(red[n], red[NHn + n]), fmaxf(red[2 * NHn + n], red[3 * NHn + n]));
    __syncthreads();

    float ls[NHn];
#pragma unroll
    for (int n = 0; n < NHn; ++n) ls[n] = 0.f;
#pragma unroll
    for (int s = 0; s < 4; ++s) {
#pragma unroll
        for (int n = 0; n < NHn; ++n) {
            sc[s][n] = expf(sc[s][n] - M[n]);
            ls[n] += sc[s][n];
        }
    }
#pragma unroll
    for (int m = 1; m < 64; m <<= 1) {
#pragma unroll
        for (int n = 0; n < NHn; ++n) ls[n] += __shfl_xor(ls[n], m, 64);
    }
    if (lane == 0) {
#pragma unroll
        for (int n = 0; n < NHn; ++n) red[wid * NHn + n] = ls[n];
    }
    __syncthreads();
    float inv[NHn];
#pragma unroll
    for (int n = 0; n < NHn; ++n) {
        const float S = red[n] + red[NHn + n] + red[2 * NHn + n] + red[3 * NHn + n];
        inv[n] = 1.0f / S;
    }

#pragma unroll
    for (int s = 0; s < 4; ++s) {
        if (ivals[s] < In) {
            float w = 0.f;
#pragma unroll
            for (int n = 0; n < NHn; ++n) w += sc[s][n] * inv[n];
            attn_out[((size_t)nb * Bn + b) * In + ivals[s]] = w;
        }
    }
}

// ---------------------------------------------------------------------------
// K3: emb[nb][b][e] = sum_i w[nb,b,i] * T[nb][sga[b,i]][e]
// 512 threads = 8 waves, each wave covers 100 genes; LDS partial reduce.
// ---------------------------------------------------------------------------
__global__ __launch_bounds__(512)
void k_emb(const int* __restrict__ sga, const float* __restrict__ attn,
           const float* __restrict__ T, float* __restrict__ emb) {
    const int b  = blockIdx.x;
    const int nb = blockIdx.y;
    __shared__ int   sv[In];
    __shared__ float sw[In];
    __shared__ float pa[8][En];  // 16 KB
    for (int idx = threadIdx.x; idx < In; idx += 512) {
        sv[idx] = sga[b * In + idx];
        sw[idx] = attn[((size_t)nb * Bn + b) * In + idx];
    }
    __syncthreads();
    const int wave = threadIdx.x >> 6, lane = threadIdx.x & 63;
    const float* Tb = T + (size_t)nb * V1 * En;
    float4 a0 = make_float4(0, 0, 0, 0), a1 = a0;
#pragma unroll 4
    for (int g = 0; g < 100; ++g) {
        const int i = wave * 100 + g;
        const int v = sv[i];
        const float w = sw[i];
        const float4* p = (const float4*)(Tb + (size_t)v * En) + lane * 2;
        const float4 t0 = p[0], t1 = p[1];
        a0.x += w * t0.x; a0.y += w * t0.y; a0.z += w * t0.z; a0.w += w * t0.w;
        a1.x += w * t1.x; a1.y += w * t1.y; a1.z += w * t1.z; a1.w += w * t1.w;
    }
    *(float4*)&pa[wave][lane * 8]     = a0;
    *(float4*)&pa[wave][lane * 8 + 4] = a1;
    __syncthreads();
    const int t = threadIdx.x;  // one E-col per thread
    float s = 0.f;
#pragma unroll
    for (int wv = 0; wv < 8; ++wv) s += pa[wv][t];
    emb[((size_t)nb * Bn + b) * En + t] = s;
}

// ---------------------------------------------------------------------------
// K4a: curr0 = relu(emb0 + can_emb[can]); hiddens[0] = curr0
// ---------------------------------------------------------------------------
__global__ __launch_bounds__(256)
void k_step0(const float* __restrict__ emb0, const int* __restrict__ can,
             const float* __restrict__ can_emb, float* __restrict__ cur,
             float* __restrict__ hid) {
    const int b = blockIdx.x;
    const int e0 = threadIdx.x * 2;
    const int c = can[b];
    float2 v = *(const float2*)(emb0 + (size_t)b * En + e0);
    const float2 ce = *(const float2*)(can_emb + (size_t)c * En + e0);
    v.x = fmaxf(v.x + ce.x, 0.f);
    v.y = fmaxf(v.y + ce.y, 0.f);
    *(float2*)(cur + (size_t)b * En + e0) = v;
    *(float2*)(hid + (size_t)b * En + e0) = v;
}

// ---------------------------------------------------------------------------
// K4b: curr = act(emb_i + prev @ Wh);  act: 0=relu, 1=sigmoid
// ---------------------------------------------------------------------------
__global__ __launch_bounds__(256)
void k_step(const float* __restrict__ embi, const float* __restrict__ prev,
            const float* __restrict__ Whi, float* __restrict__ cur,
            float* __restrict__ hid, const int sig) {
    const int b = blockIdx.x;
    __shared__ float cr[En];
    cr[threadIdx.x]       = prev[(size_t)b * En + threadIdx.x];
    cr[threadIdx.x + 256] = prev[(size_t)b * En + threadIdx.x + 256];
    __syncthreads();
    const int e0 = threadIdx.x * 2;
    float2 a = *(const float2*)(embi + (size_t)b * En + e0);
    const float2* Wp = (const float2*)Whi;
#pragma unroll 4
    for (int k = 0; k < En; ++k) {
        const float ck = cr[k];
        const float2 wv = Wp[(size_t)k * (En / 2) + threadIdx.x];
        a.x += ck * wv.x;
        a.y += ck * wv.y;
    }
    if (sig) {
        a.x = 1.0f / (1.0f + expf(-a.x));
        a.y = 1.0f / (1.0f + expf(-a.y));
    } else {
        a.x = fmaxf(a.x, 0.f);
        a.y = fmaxf(a.y, 0.f);
    }
    *(float2*)(cur + (size_t)b * En + e0) = a;
    *(float2*)(hid + (size_t)b * En + e0) = a;
}

// ---------------------------------------------------------------------------
// K5: preds = curr3 @ Wfinal   [128,512]@[512,5000]
// ---------------------------------------------------------------------------
__global__ __launch_bounds__(256, 2)
void k_preds(const float* __restrict__ cur, const float* __restrict__ Wf,
             float* __restrict__ preds) {
    __shared__ float cs[32 * En];  // 64 KB
    const int nt = blockIdx.x;
    const int bt = blockIdx.y;
    for (int idx = threadIdx.x; idx < 32 * 128; idx += 256) {
        const int row = idx >> 7;
        const int c4  = (idx & 127) << 2;
        *(float4*)(cs + row * En + c4) =
            *(const float4*)(cur + (size_t)(bt * 32 + row) * En + c4);
    }
    __syncthreads();
    const int lane = threadIdx.x & 63;
    const int rgrp = threadIdx.x >> 6;
    const int col = nt * 64 + lane;
    float acc[8];
#pragma unroll
    for (int j = 0; j < 8; ++j) acc[j] = 0.f;
    const bool ok = (col < OUTn);
    for (int k = 0; k < En; k += 4) {
        float w0 = 0.f, w1 = 0.f, w2 = 0.f, w3 = 0.f;
        if (ok) {
            w0 = Wf[(size_t)(k + 0) * OUTn + col];
            w1 = Wf[(size_t)(k + 1) * OUTn + col];
            w2 = Wf[(size_t)(k + 2) * OUTn + col];
            w3 = Wf[(size_t)(k + 3) * OUTn + col];
        }
#pragma unroll
        for (int j = 0; j < 8; ++j) {
            const float4 cv = *(const float4*)(cs + (rgrp * 8 + j) * En + k);
            acc[j] += cv.x * w0 + cv.y * w1 + cv.z * w2 + cv.w * w3;
        }
    }
    if (ok) {
#pragma unroll
        for (int j = 0; j < 8; ++j)
            preds[(size_t)(bt * 32 + rgrp * 8 + j) * OUTn + col] = acc[j];
    }
}

// ---------------------------------------------------------------------------
extern "C" void kernel_launch(void* const* d_in, const int* in_sizes, int n_in,
                              void* d_out, int out_size, void* d_ws, size_t ws_size,
                              hipStream_t stream) {
    const int*   sga     = (const int*)d_in[0];
    const int*   can     = (const int*)d_in[1];
    const float* T       = (const float*)d_in[2];
    const float* Wk      = (const float*)d_in[3];
    const float* bk      = (const float*)d_in[4];
    const float* Wq      = (const float*)d_in[5];
    // d_in[6] = bq: unused — constant over softmax axis, cancels exactly
    const float* can_emb = (const float*)d_in[7];
    const float* Wh      = (const float*)d_in[8];
    const float* Wf      = (const float*)d_in[9];

    float* out = (float*)d_out;
    float* ws  = (float*)d_ws;

    // workspace layout (floats; 16B-aligned)
    float* scoresv = ws;                                // NB*V1*NH   = 608032
    float* embw    = scoresv + (size_t)NBn * V1 * NHn;  // NB*B*E     = 262144
    float* cur0    = embw + (size_t)NBn * Bn * En;      // B*E
    float* cur1    = cur0 + (size_t)Bn * En;            // B*E
    ushort* Wkt    = (ushort*)(cur1 + (size_t)Bn * En); // NB*E*E bf16 = 2 MB

    float* preds_out = out;
    float* attn_out  = out + OFF_ATTN;
    float* hid_out   = out + OFF_HID;

    const int nsc = NBn * V1 * NHn;

    // K0: Wk -> bf16 transposed [nb][n][k] (LDS tile transpose)
    k_prep<<<dim3(8, 8, NBn), 256, 0, stream>>>(Wk, Wkt);
    // zero the atomic accumulator
    k_zero<<<(nsc + 255) / 256, 256, 0, stream>>>(scoresv, nsc);
    // K1: fused keys-GEMM + scores epilogue (atomic partials)
    k_scores<<<dim3((V1 + 127) / 128, 4, NBn), 256, 0, stream>>>(T, Wkt, bk, Wq, scoresv);
    // K2: softmax + head-sum -> attns (directly to d_out)
    k_softmax<<<dim3(Bn, NBn), 256, 0, stream>>>(sga, scoresv, attn_out);
    // K3: weighted embedding sums
    k_emb<<<dim3(Bn, NBn), 512, 0, stream>>>(sga, attn_out, T, embw);
    // K4: residual chain
    k_step0<<<Bn, 256, 0, stream>>>(embw, can, can_emb, cur0, hid_out);
    k_step<<<Bn, 256, 0, stream>>>(embw + 1 * Bn * En, cur0, Wh + 0 * En * En,
                                   cur1, hid_out + 1 * (size_t)Bn * En, 0);
    k_step<<<Bn, 256, 0, stream>>>(embw + 2 * Bn * En, cur1, Wh + 1 * En * En,
                                   cur0, hid_out + 2 * (size_t)Bn * En, 0);
    k_step<<<Bn, 256, 0, stream>>>(embw + 3 * Bn * En, cur0, Wh + 2 * En * En,
                                   cur1, hid_out + 3 * (size_t)Bn * En, 1);
    // K5: final projection
    k_preds<<<dim3((OUTn + 63) / 64, Bn / 32), 256, 0, stream>>>(cur1, Wf, preds_out);
}

// Round 4
// 576.448 us; speedup vs baseline: 2.1375x; 1.2970x over previous
//
#include <hip/hip_runtime.h>
#include <hip/hip_bf16.h>

// Problem constants
constexpr int Bn   = 128;    // batch
constexpr int In   = 800;    // genes per case
constexpr int En   = 512;    // embed dim
constexpr int V1   = 19001;  // vocab + padding row
constexpr int NHn  = 8;      // heads
constexpr int NBn  = 4;      // attention blocks
constexpr int OUTn = 5000;   // output genes

// d_out layout (floats): preds [B,OUT] | attns [NB,B,I] | hiddens [NB,B,E]
constexpr int OFF_ATTN = Bn * OUTn;                 // 640000
constexpr int OFF_HID  = OFF_ATTN + NBn * Bn * In;  // 1049600

typedef __attribute__((ext_vector_type(8))) short bf16x8;
typedef __attribute__((ext_vector_type(8))) unsigned short u16x8;
typedef __attribute__((ext_vector_type(4))) float f32x4;

__device__ inline ushort f2bf(float x) {
    __hip_bfloat16 h = __float2bfloat16(x);
    return *reinterpret_cast<ushort*>(&h);
}
__device__ inline float bf2f(ushort u) {
    return __uint_as_float(((unsigned)u) << 16);
}
__device__ inline void gl_lds16(const ushort* g, ushort* l) {
    __builtin_amdgcn_global_load_lds(
        (const __attribute__((address_space(1))) void*)g,
        (__attribute__((address_space(3))) void*)l, 16, 0, 0);
}

// ---------------------------------------------------------------------------
// K0: Wkt[nb][n][k] = bf16(Wk[nb][k][n]) via LDS tile transpose (coalesced IO)
// ---------------------------------------------------------------------------
__global__ __launch_bounds__(256)
void k_prep(const float* __restrict__ Wk, ushort* __restrict__ Wkt) {
    __shared__ float ts[64][65];
    const int n0 = blockIdx.x * 64, k0 = blockIdx.y * 64, nb = blockIdx.z;
    const int t = threadIdx.x;
    {
        const int kr = t >> 2, nc = (t & 3) * 16;
        const float* p = Wk + (((size_t)nb * En) + (k0 + kr)) * En + n0 + nc;
#pragma unroll
        for (int j = 0; j < 4; ++j) {
            const float4 v = *(const float4*)(p + j * 4);
            ts[kr][nc + j * 4 + 0] = v.x; ts[kr][nc + j * 4 + 1] = v.y;
            ts[kr][nc + j * 4 + 2] = v.z; ts[kr][nc + j * 4 + 3] = v.w;
        }
    }
    __syncthreads();
    {
        const int nr = t >> 2, kc = (t & 3) * 16;
        ushort* d = Wkt + (((size_t)nb * En) + (n0 + nr)) * En + k0 + kc;
        ushort4 o;
#pragma unroll
        for (int j = 0; j < 4; ++j) {
            o.x = f2bf(ts[kc + j * 4 + 0][nr]); o.y = f2bf(ts[kc + j * 4 + 1][nr]);
            o.z = f2bf(ts[kc + j * 4 + 2][nr]); o.w = f2bf(ts[kc + j * 4 + 3][nr]);
            *(ushort4*)(d + j * 4) = o;
        }
    }
}

// ---------------------------------------------------------------------------
// K1: scoresv[nb][v][h] from keys = tanh(T@Wk+bk), scores = keys@Wq.
// Block tile M=64 x N=512 (A read exactly once per launch), BK=32, 16 iters,
// double-buffered: glds B[next] + A[next]->regs issued before current MFMAs.
// 4 waves, wave tile 64x128 (acc[4][8]). Epilogue: tanh + per-head VALU dot
// + 16-lane butterfly + cross-wave LDS reduce -> direct scoresv stores.
// Optionally side-stores bf16 A rows to Tbf for k_emb.
// ---------------------------------------------------------------------------
template <bool TBF>
__global__ __launch_bounds__(256, 2)
void k_scores(const float* __restrict__ T, const ushort* __restrict__ Wkt,
              const float* __restrict__ bk, const float* __restrict__ Wq,
              float* __restrict__ scoresv, ushort* __restrict__ Tbf) {
    __shared__ ushort Bs[2][512][32];                                  // 64 KB
    __shared__ union { ushort A[2][64][32]; float red[4][64][NHn]; } u;  // 8 KB

    const int mblk = blockIdx.x, nb = blockIdx.y;
    const int v0 = mblk * 64;
    const int tid = threadIdx.x, lane = tid & 63, w = tid >> 6;
    const int q = lane >> 4, c = lane & 15;

    const float*  Tb = T + (size_t)nb * V1 * En;
    const ushort* Wn = Wkt + (size_t)nb * En * En;

    // A staging map: thread t -> row t>>2 (0..63), 8-float chunk t&3
    const int arow = tid >> 2, akq = tid & 3;
    const int vra = v0 + arow;
    const float* agp = Tb + (size_t)vra * En + akq * 8;
    ushort* tsp = Tbf + ((size_t)nb * V1 + vra) * En + akq * 8;

    f32x4 acc[4][8];
#pragma unroll
    for (int mt = 0; mt < 4; ++mt)
#pragma unroll
        for (int nt = 0; nt < 8; ++nt) acc[mt][nt] = (f32x4)0.0f;

    auto stageB = [&](int buf, int k0) {
#pragma unroll
        for (int j = 0; j < 8; ++j) {
            const int nrow = (w * 8 + j) * 16;
            const ushort* gp =
                Wn + (size_t)(nrow + (lane >> 2)) * En + k0 + (lane & 3) * 8;
            gl_lds16(gp, &Bs[buf][nrow][0]);
        }
    };
    auto loadA = [&](int k0, float4& f0, float4& f1) {
        if (vra < V1) {
            f0 = *(const float4*)(agp + k0);
            f1 = *(const float4*)(agp + k0 + 4);
        } else {
            f0 = make_float4(0.f, 0.f, 0.f, 0.f);
            f1 = f0;
        }
    };
    auto writeA = [&](int buf, int k0, float4 f0, float4 f1) {
        u16x8 o;
        o[0] = f2bf(f0.x); o[1] = f2bf(f0.y); o[2] = f2bf(f0.z); o[3] = f2bf(f0.w);
        o[4] = f2bf(f1.x); o[5] = f2bf(f1.y); o[6] = f2bf(f1.z); o[7] = f2bf(f1.w);
        *(u16x8*)&u.A[buf][arow][akq * 8] = o;
        if (TBF && vra < V1) *(u16x8*)(tsp + k0) = o;
    };

    // prologue: stage iteration 0
    stageB(0, 0);
    {
        float4 f0, f1;
        loadA(0, f0, f1);
        writeA(0, 0, f0, f1);
    }
    __syncthreads();

    for (int it = 0; it < 16; ++it) {
        const int cur = it & 1, nxt = cur ^ 1;
        const int k0n = (it + 1) * 32;
        float4 p0, p1;
        if (it < 15) {
            stageB(nxt, k0n);   // async into other buffer, no wait
            loadA(k0n, p0, p1); // prefetch A into regs, no use yet
        }
        bf16x8 aF[4], bF[8];
#pragma unroll
        for (int mt = 0; mt < 4; ++mt)
            aF[mt] = *(bf16x8*)&u.A[cur][mt * 16 + c][q * 8];
#pragma unroll
        for (int nt = 0; nt < 8; ++nt)
            bF[nt] = *(bf16x8*)&Bs[cur][w * 128 + nt * 16 + c][q * 8];
#pragma unroll
        for (int nt = 0; nt < 8; ++nt)
#pragma unroll
            for (int mt = 0; mt < 4; ++mt)
                acc[mt][nt] = __builtin_amdgcn_mfma_f32_16x16x32_bf16(
                    aF[mt], bF[nt], acc[mt][nt], 0, 0, 0);
        if (it < 15) writeA(nxt, k0n, p0, p1);
        __syncthreads();  // drains glds B[nxt] + A writes; overlapped w/ MFMAs
    }

    // --- epilogue: keys = tanh(acc + bk[col]) in-register ---
#pragma unroll
    for (int nt = 0; nt < 8; ++nt) {
        const int col = w * 128 + nt * 16 + c;
        const float bkv = bk[nb * En + col];
#pragma unroll
        for (int mt = 0; mt < 4; ++mt)
#pragma unroll
            for (int r = 0; r < 4; ++r)
                acc[mt][nt][r] = tanhf(acc[mt][nt][r] + bkv);
    }

    // --- scores: per head, dot over this wave's 128 cols + 16-lane butterfly
    for (int h = 0; h < NHn; ++h) {
        float wqh[8];
#pragma unroll
        for (int nt = 0; nt < 8; ++nt) {
            const int col = w * 128 + nt * 16 + c;
            wqh[nt] = Wq[((size_t)nb * En + col) * NHn + h];
        }
        float p[4][4];
#pragma unroll
        for (int mt = 0; mt < 4; ++mt)
#pragma unroll
            for (int r = 0; r < 4; ++r) {
                float s = 0.f;
#pragma unroll
                for (int nt = 0; nt < 8; ++nt) s += acc[mt][nt][r] * wqh[nt];
                p[mt][r] = s;
            }
#pragma unroll
        for (int m = 1; m < 16; m <<= 1) {
#pragma unroll
            for (int mt = 0; mt < 4; ++mt)
#pragma unroll
                for (int r = 0; r < 4; ++r)
                    p[mt][r] += __shfl_xor(p[mt][r], m, 64);
        }
        if (c == h) {
#pragma unroll
            for (int mt = 0; mt < 4; ++mt)
#pragma unroll
                for (int r = 0; r < 4; ++r)
                    u.red[w][mt * 16 + q * 4 + r][h] = p[mt][r];
        }
    }
    __syncthreads();

    // --- cross-wave reduce, direct store (bq dropped: cancels in softmax) ---
    for (int idx = tid; idx < 64 * NHn; idx += 256) {
        const int row = idx >> 3, h = idx & 7;
        const int vr = v0 + row;
        if (vr < V1)
            scoresv[((size_t)nb * V1 + vr) * NHn + h] =
                u.red[0][row][h] + u.red[1][row][h] +
                u.red[2][row][h] + u.red[3][row][h];
    }
}

// ---------------------------------------------------------------------------
// K2: masked softmax over genes, per (nb, b); writes attn weights (head-sum).
// ---------------------------------------------------------------------------
__global__ __launch_bounds__(256)
void k_softmax(const int* __restrict__ sga, const float* __restrict__ scoresv,
               float* __restrict__ attn_out) {
    const int b  = blockIdx.x;
    const int nb = blockIdx.y;
    const int tid = threadIdx.x;
    const int lane = tid & 63;
    const int wid  = tid >> 6;
    __shared__ float red[4 * NHn];

    float sc[4][NHn];
    int ivals[4];
#pragma unroll
    for (int s = 0; s < 4; ++s) {
        const int i = tid + s * 256;
        ivals[s] = i;
        if (i < In) {
            const int v = sga[b * In + i];
            const float4 s0 = *(const float4*)(scoresv + ((size_t)nb * V1 + v) * NHn);
            const float4 s1 = *(const float4*)(scoresv + ((size_t)nb * V1 + v) * NHn + 4);
            sc[s][0] = s0.x; sc[s][1] = s0.y; sc[s][2] = s0.z; sc[s][3] = s0.w;
            sc[s][4] = s1.x; sc[s][5] = s1.y; sc[s][6] = s1.z; sc[s][7] = s1.w;
            if (v == 0) {
#pragma unroll
                for (int n = 0; n < NHn; ++n) sc[s][n] = -1e9f;
            }
        } else {
#pragma unroll
            for (int n = 0; n < NHn; ++n) sc[s][n] = -3.0e38f;
        }
    }

    float lm[NHn];
#pragma unroll
    for (int n = 0; n < NHn; ++n)
        lm[n] = fmaxf(fmaxf(sc[0][n], sc[1][n]), fmaxf(sc[2][n], sc[3][n]));
#pragma unroll
    for (int m = 1; m < 64; m <<= 1) {
#pragma unroll
        for (int n = 0; n < NHn; ++n) lm[n] = fmaxf(lm[n], __shfl_xor(lm[n], m, 64));
    }
    if (lane == 0) {
#pragma unroll
        for (int n = 0; n < NHn; ++n) red[wid * NHn + n] = lm[n];
    }
    __syncthreads();
    float M[NHn];
#pragma unroll
    for (int n = 0; n < NHn; ++n)
        M[n] = fmaxf(fmaxf(red[n], red[NHn + n]), fmaxf(red[2 * NHn + n], red[3 * NHn + n]));
    __syncthreads();

    float ls[NHn];
#pragma unroll
    for (int n = 0; n < NHn; ++n) ls[n] = 0.f;
#pragma unroll
    for (int s = 0; s < 4; ++s) {
#pragma unroll
        for (int n = 0; n < NHn; ++n) {
            sc[s][n] = expf(sc[s][n] - M[n]);
            ls[n] += sc[s][n];
        }
    }
#pragma unroll
    for (int m = 1; m < 64; m <<= 1) {
#pragma unroll
        for (int n = 0; n < NHn; ++n) ls[n] += __shfl_xor(ls[n], m, 64);
    }
    if (lane == 0) {
#pragma unroll
        for (int n = 0; n < NHn; ++n) red[wid * NHn + n] = ls[n];
    }
    __syncthreads();
    float inv[NHn];
#pragma unroll
    for (int n = 0; n < NHn; ++n) {
        const float S = red[n] + red[NHn + n] + red[2 * NHn + n] + red[3 * NHn + n];
        inv[n] = 1.0f / S;
    }

#pragma unroll
    for (int s = 0; s < 4; ++s) {
        if (ivals[s] < In) {
            float w = 0.f;
#pragma unroll
            for (int n = 0; n < NHn; ++n) w += sc[s][n] * inv[n];
            attn_out[((size_t)nb * Bn + b) * In + ivals[s]] = w;
        }
    }
}

// ---------------------------------------------------------------------------
// K3: emb[nb][b][e] = sum_i w[nb,b,i] * T[nb][sga[b,i]][e]
// 512 threads = 8 waves x 100 genes; LDS partial reduce.
// TBF variant gathers bf16 rows (half the L3 traffic).
// ---------------------------------------------------------------------------
template <bool TBF>
__global__ __launch_bounds__(512)
void k_emb(const int* __restrict__ sga, const float* __restrict__ attn,
           const float* __restrict__ T, const ushort* __restrict__ Tbf,
           float* __restrict__ emb) {
    const int b  = blockIdx.x;
    const int nb = blockIdx.y;
    __shared__ int   sv[In];
    __shared__ float sw[In];
    __shared__ float pa[8][En];  // 16 KB
    for (int idx = threadIdx.x; idx < In; idx += 512) {
        sv[idx] = sga[b * In + idx];
        sw[idx] = attn[((size_t)nb * Bn + b) * In + idx];
    }
    __syncthreads();
    const int wave = threadIdx.x >> 6, lane = threadIdx.x & 63;
    float a[8];
#pragma unroll
    for (int j = 0; j < 8; ++j) a[j] = 0.f;

    if (TBF) {
        const ushort* Tb = Tbf + (size_t)nb * V1 * En;
#pragma unroll 4
        for (int g = 0; g < 100; ++g) {
            const int i = wave * 100 + g;
            const int v = sv[i];
            const float w = sw[i];
            const u16x8 t = *(const u16x8*)(Tb + (size_t)v * En + lane * 8);
#pragma unroll
            for (int j = 0; j < 8; ++j) a[j] += w * bf2f(t[j]);
        }
    } else {
        const float* Tb = T + (size_t)nb * V1 * En;
#pragma unroll 4
        for (int g = 0; g < 100; ++g) {
            const int i = wave * 100 + g;
            const int v = sv[i];
            const float w = sw[i];
            const float4* p = (const float4*)(Tb + (size_t)v * En) + lane * 2;
            const float4 t0 = p[0], t1 = p[1];
            a[0] += w * t0.x; a[1] += w * t0.y; a[2] += w * t0.z; a[3] += w * t0.w;
            a[4] += w * t1.x; a[5] += w * t1.y; a[6] += w * t1.z; a[7] += w * t1.w;
        }
    }
#pragma unroll
    for (int j = 0; j < 8; ++j) pa[wave][lane * 8 + j] = a[j];
    __syncthreads();
    const int t = threadIdx.x;
    float s = 0.f;
#pragma unroll
    for (int wv = 0; wv < 8; ++wv) s += pa[wv][t];
    emb[((size_t)nb * Bn + b) * En + t] = s;
}

// ---------------------------------------------------------------------------
// K4a: curr0 = relu(emb0 + can_emb[can]); hiddens[0] = curr0
// ---------------------------------------------------------------------------
__global__ __launch_bounds__(256)
void k_step0(const float* __restrict__ emb0, const int* __restrict__ can,
             const float* __restrict__ can_emb, float* __restrict__ cur,
             float* __restrict__ hid) {
    const int b = blockIdx.x;
    const int e0 = threadIdx.x * 2;
    const int c = can[b];
    float2 v = *(const float2*)(emb0 + (size_t)b * En + e0);
    const float2 ce = *(const float2*)(can_emb + (size_t)c * En + e0);
    v.x = fmaxf(v.x + ce.x, 0.f);
    v.y = fmaxf(v.y + ce.y, 0.f);
    *(float2*)(cur + (size_t)b * En + e0) = v;
    *(float2*)(hid + (size_t)b * En + e0) = v;
}

// ---------------------------------------------------------------------------
// K4b: curr = act(emb_i + prev @ Wh), K-split over 2 half-ranges,
// grid (b, 4 col-chunks) = 512 blocks.  act: 0=relu, 1=sigmoid
// ---------------------------------------------------------------------------
__global__ __launch_bounds__(256)
void k_step(const float* __restrict__ embi, const float* __restrict__ prev,
            const float* __restrict__ Whi, float* __restrict__ cur,
            float* __restrict__ hid, const int sig) {
    const int b = blockIdx.x, cc = blockIdx.y;
    __shared__ float pr[En];
    __shared__ float part[2][128];
    pr[threadIdx.x]       = prev[(size_t)b * En + threadIdx.x];
    pr[threadIdx.x + 256] = prev[(size_t)b * En + threadIdx.x + 256];
    __syncthreads();
    const int col = cc * 128 + (threadIdx.x & 127);
    const int kh  = threadIdx.x >> 7;
    float s = 0.f;
    const float* Wp = Whi + (size_t)(kh * 256) * En + col;
#pragma unroll 8
    for (int k = 0; k < 256; ++k) s += pr[kh * 256 + k] * Wp[(size_t)k * En];
    part[kh][threadIdx.x & 127] = s;
    __syncthreads();
    if (threadIdx.x < 128) {
        float a = part[0][threadIdx.x] + part[1][threadIdx.x] +
                  embi[(size_t)b * En + col];
        if (sig) a = 1.0f / (1.0f + expf(-a));
        else     a = fmaxf(a, 0.f);
        cur[(size_t)b * En + col] = a;
        hid[(size_t)b * En + col] = a;
    }
}

// ---------------------------------------------------------------------------
// K5: preds = curr3 @ Wfinal   [128,512]@[512,5000]
// ---------------------------------------------------------------------------
__global__ __launch_bounds__(256, 2)
void k_preds(const float* __restrict__ cur, const float* __restrict__ Wf,
             float* __restrict__ preds) {
    __shared__ float cs[32 * En];  // 64 KB
    const int nt = blockIdx.x;
    const int bt = blockIdx.y;
    for (int idx = threadIdx.x; idx < 32 * 128; idx += 256) {
        const int row = idx >> 7;
        const int c4  = (idx & 127) << 2;
        *(float4*)(cs + row * En + c4) =
            *(const float4*)(cur + (size_t)(bt * 32 + row) * En + c4);
    }
    __syncthreads();
    const int lane = threadIdx.x & 63;
    const int rgrp = threadIdx.x >> 6;
    const int col = nt * 64 + lane;
    float acc[8];
#pragma unroll
    for (int j = 0; j < 8; ++j) acc[j] = 0.f;
    const bool ok = (col < OUTn);
    for (int k = 0; k < En; k += 4) {
        float w0 = 0.f, w1 = 0.f, w2 = 0.f, w3 = 0.f;
        if (ok) {
            w0 = Wf[(size_t)(k + 0) * OUTn + col];
            w1 = Wf[(size_t)(k + 1) * OUTn + col];
            w2 = Wf[(size_t)(k + 2) * OUTn + col];
            w3 = Wf[(size_t)(k + 3) * OUTn + col];
        }
#pragma unroll
        for (int j = 0; j < 8; ++j) {
            const float4 cv = *(const float4*)(cs + (rgrp * 8 + j) * En + k);
            acc[j] += cv.x * w0 + cv.y * w1 + cv.z * w2 + cv.w * w3;
        }
    }
    if (ok) {
#pragma unroll
        for (int j = 0; j < 8; ++j)
            preds[(size_t)(bt * 32 + rgrp * 8 + j) * OUTn + col] = acc[j];
    }
}

// ---------------------------------------------------------------------------
extern "C" void kernel_launch(void* const* d_in, const int* in_sizes, int n_in,
                              void* d_out, int out_size, void* d_ws, size_t ws_size,
                              hipStream_t stream) {
    const int*   sga     = (const int*)d_in[0];
    const int*   can     = (const int*)d_in[1];
    const float* T       = (const float*)d_in[2];
    const float* Wk      = (const float*)d_in[3];
    const float* bk      = (const float*)d_in[4];
    const float* Wq      = (const float*)d_in[5];
    // d_in[6] = bq: unused — constant over softmax axis, cancels exactly
    const float* can_emb = (const float*)d_in[7];
    const float* Wh      = (const float*)d_in[8];
    const float* Wf      = (const float*)d_in[9];

    float* out = (float*)d_out;
    float* ws  = (float*)d_ws;

    // workspace layout (floats; all 16B-aligned)
    float* scoresv = ws;                                // NB*V1*NH   = 608032
    float* embw    = scoresv + (size_t)NBn * V1 * NHn;  // NB*B*E     = 262144
    float* cur0    = embw + (size_t)NBn * Bn * En;      // B*E
    float* cur1    = cur0 + (size_t)Bn * En;            // B*E
    ushort* Wkt    = (ushort*)(cur1 + (size_t)Bn * En); // NB*E*E bf16 = 2 MB
    ushort* Tbf    = Wkt + (size_t)NBn * En * En;       // NB*V1*E bf16 = 78 MB
    const size_t need_full =
        (size_t)(scoresv - ws) * 4 +
        ((size_t)NBn * V1 * NHn + (size_t)NBn * Bn * En + 2 * (size_t)Bn * En) * 4 +
        (size_t)NBn * En * En * 2 + (size_t)NBn * V1 * En * 2;
    const bool useTbf = (ws_size >= need_full);

    float* preds_out = out;
    float* attn_out  = out + OFF_ATTN;
    float* hid_out   = out + OFF_HID;

    // K0: Wk -> bf16 transposed [nb][n][k]
    k_prep<<<dim3(8, 8, NBn), 256, 0, stream>>>(Wk, Wkt);
    // K1: fused keys-GEMM + scores epilogue (direct stores, no atomics)
    if (useTbf)
        k_scores<true><<<dim3((V1 + 63) / 64, NBn), 256, 0, stream>>>(
            T, Wkt, bk, Wq, scoresv, Tbf);
    else
        k_scores<false><<<dim3((V1 + 63) / 64, NBn), 256, 0, stream>>>(
            T, Wkt, bk, Wq, scoresv, Tbf);
    // K2: softmax + head-sum -> attns (directly to d_out)
    k_softmax<<<dim3(Bn, NBn), 256, 0, stream>>>(sga, scoresv, attn_out);
    // K3: weighted embedding sums (bf16 gather if Tbf available)
    if (useTbf)
        k_emb<true><<<dim3(Bn, NBn), 512, 0, stream>>>(sga, attn_out, T, Tbf, embw);
    else
        k_emb<false><<<dim3(Bn, NBn), 512, 0, stream>>>(sga, attn_out, T, Tbf, embw);
    // K4: residual chain
    k_step0<<<Bn, 256, 0, stream>>>(embw, can, can_emb, cur0, hid_out);
    k_step<<<dim3(Bn, 4), 256, 0, stream>>>(embw + 1 * Bn * En, cur0,
                                            Wh + 0 * En * En, cur1,
                                            hid_out + 1 * (size_t)Bn * En, 0);
    k_step<<<dim3(Bn, 4), 256, 0, stream>>>(embw + 2 * Bn * En, cur1,
                                            Wh + 1 * En * En, cur0,
                                            hid_out + 2 * (size_t)Bn * En, 0);
    k_step<<<dim3(Bn, 4), 256, 0, stream>>>(embw + 3 * Bn * En, cur0,
                                            Wh + 2 * En * En, cur1,
                                            hid_out + 3 * (size_t)Bn * En, 1);
    // K5: final projection
    k_preds<<<dim3((OUTn + 63) / 64, Bn / 32), 256, 0, stream>>>(cur1, Wf, preds_out);
}